// Round 12
// baseline (430.975 us; speedup 1.0000x reference)
//
#include <hip/hip_runtime.h>
#include <stdint.h>

#define BB 32
#define LL 1024
#define CC 512
#define NN (BB * LL)      // 32768 positions
#define NLEVS 4
#define OUTD 11
#define LPAD 8            // zero pad rows per sequence (>= max dilation)
#define LROWS (LL + LPAD) // 1032 padded rows per sequence

typedef __attribute__((ext_vector_type(8))) short bf16x8;
typedef __attribute__((ext_vector_type(4))) float f32x4;

static __device__ __forceinline__ unsigned short f2bf(float f) {
    union { float f; uint32_t u; } v; v.f = f;
    uint32_t u = v.u;
    uint32_t r = (u + 0x7fffu + ((u >> 16) & 1u)) >> 16;  // RNE
    return (unsigned short)r;
}
static __device__ __forceinline__ float bf2f(unsigned short h) {
    union { uint32_t u; float f; } v; v.u = ((uint32_t)h) << 16;
    return v.f;
}

// async 16B global -> LDS (wave-uniform LDS base + lane*16)
static __device__ __forceinline__ void llds16(const unsigned short* g, unsigned short* l) {
    __builtin_amdgcn_global_load_lds(
        (const __attribute__((address_space(1))) unsigned int*)g,
        (__attribute__((address_space(3))) unsigned int*)l, 16, 0, 0);
}

// Fused prep: pack_w | embed | zero_pad | pack_dw, selected by block range.
__global__ __launch_bounds__(256) void prep_kernel(
    const int* __restrict__ x, const float* __restrict__ emb,
    const float* __restrict__ w1, const float* __restrict__ w2,
    const float* __restrict__ dw,
    unsigned short* __restrict__ Hb0, unsigned short* __restrict__ Hb1,
    unsigned short* __restrict__ WpT, unsigned short* __restrict__ dwp)
{
    int b = blockIdx.x;
    if (b < 16384) {
        // WpT[cv][j][co][h]; kidx=j*8+h; kidx<512 -> tap k=1 (current), else k=0
        int e = b * 256 + threadIdx.x;
        int cv = e >> 19;
        int r = e & 524287;
        int j = r >> 12;
        int co = (r >> 3) & 511;
        int h = r & 7;
        int kidx = j * 8 + h;
        int k = (kidx < 512) ? 1 : 0;
        int ci = kidx & 511;
        int lvl = cv >> 1;
        const float* w = (cv & 1) ? w2 : w1;
        WpT[e] = f2bf(w[(((size_t)(lvl * 512 + co) * 512) + ci) * 2 + k]);
    } else if (b < 24576) {
        int t = (b - 16384) * 256 + threadIdx.x;
        int n = t >> 6;
        int c8 = (t & 63) * 8;
        int idx = x[n];
        const float* src = emb + (size_t)idx * CC + c8;
        float4 v0 = *(const float4*)src;
        float4 v1 = *(const float4*)(src + 4);
        ushort4 a, bb;
        a.x = f2bf(v0.x); a.y = f2bf(v0.y); a.z = f2bf(v0.z); a.w = f2bf(v0.w);
        bb.x = f2bf(v1.x); bb.y = f2bf(v1.y); bb.z = f2bf(v1.z); bb.w = f2bf(v1.w);
        int prow = (n >> 10) * LROWS + LPAD + (n & (LL - 1));
        unsigned short* dst = Hb0 + (size_t)prow * CC + c8;
        *(ushort4*)dst = a;
        *(ushort4*)(dst + 4) = bb;
    } else if (b < 24704) {
        int t = (b - 24576) * 256 + threadIdx.x;   // 32768 uint4 stores
        unsigned short* base = (t >> 14) ? Hb1 : Hb0;
        int rem = t & 16383;
        int p = rem >> 9;
        int q = rem & 511;
        size_t off = (size_t)p * (LROWS * CC) + (size_t)q * 8;
        *(uint4*)(base + off) = (uint4){0u, 0u, 0u, 0u};
    } else {
        int e = (b - 24704) * 256 + threadIdx.x;   // 8192 halves
        int jb = e >> 7;
        int o = (e >> 3) & 15;
        int j = e & 7;
        dwp[e] = f2bf((o < OUTD) ? dw[o * CC + jb * 8 + j] : 0.f);
    }
}

// GEMM: out[n][co] = act( A-window . W + bias ), all activations bf16.
// 128n x 128co tile; each of 4 waves is a FULLY SELF-PACED 64n x 64co pipeline:
// private 72-row A window ([wm-8, wm+64)) in a private 2-slot LDS region, so
// there is NO cross-wave sync (no barriers, flags, or spins) in the K-loop.
// Per it: preload 16 B frags (whole it) -> issue 9 A-DMAs for it+1 ->
// s_waitcnt vmcnt(9) (drains B(it)+A(it); leaves A(it+1) in flight through the
// whole compute phase) -> 64 MFMAs. 16x16x32 MFMA 4x4/wave; 128-B-pitch XOR-
// swizzled LDS (measured-zero-conflict). B direct from global (k-major WpT).
// XCD swizzle: 4 co-blocks of an n-window land on one XCD.
// HAS_RES: v = relu(relu(acc+b) + res_bf16); in-place-safe (lane-owned elems).
#define WBUF (72 * 64)    // halves per slot: 72 rows x 64 halves = 9216 B
template <bool HAS_RES>
__global__ __launch_bounds__(256, 2) void conv_gemm(
    const unsigned short* __restrict__ Ain, const unsigned short* __restrict__ WpT,
    const float* __restrict__ bias, const unsigned short* __restrict__ resB,
    unsigned short* __restrict__ OutB, int d)
{
    __shared__ unsigned short sA[4][2 * WBUF];   // [wave][slot 0/1]

    const int tid = threadIdx.x;
    const int wave = tid >> 6, lane = tid & 63;

    const int bid = blockIdx.x;               // 0..1023
    const int xcd = bid & 7;
    const int local = bid >> 3;               // 0..127
    const int cb = local >> 5;                // 0..3
    const int nb = xcd + 8 * (local & 31);    // 0..255
    const int co0 = cb * 128;
    const int n0 = nb * 128;

    const int rbase = (n0 >> 10) * LROWS + LPAD + (n0 & (LL - 1));
    const int wm = (wave >> 1) * 64;           // wave n-stripe
    const int wn = (wave & 1) * 64;            // wave co-stripe
    const int lm = lane & 15, quad = lane >> 4;

    // staging lane decomposition: 8 rows x 8 chunks of 16B per llds16 (1 KB)
    const int r8 = lane >> 3;
    const int c8 = lane & 7;

    // wave-private global staging base: row rbase+wm-8 (rbase+wm-8 ≡ 0 mod 8,
    // so within-slot row ≡ global row mod 8 and the XOR key matches reads)
    const unsigned short* gAw =
        Ain + (size_t)(rbase + wm - 8 + r8) * CC + (c8 ^ r8) * 8;
    unsigned short* const slot0 = sA[wave];
    unsigned short* const slot1 = sA[wave] + WBUF;

    // issue this wave's full 72-row window for ci-block `it` into slot it&1
    auto issueA = [&](int it) {
        const unsigned short* g = gAw + it * 64;
        unsigned short* l = (it & 1) ? slot1 : slot0;
#pragma unroll
        for (int seg = 0; seg < 9; ++seg)
            llds16(g + (size_t)seg * 8 * CC, l + seg * 512);
    };

    f32x4 acc[4][4];
#pragma unroll
    for (int i = 0; i < 4; ++i)
#pragma unroll
        for (int j = 0; j < 4; ++j) acc[i][j] = (f32x4){0.f, 0.f, 0.f, 0.f};

    issueA(0);

    for (int it = 0; it < 8; ++it) {
        // preload ALL 16 B fragments of this it (order matters: B before A-DMAs
        // so vmcnt(9) drains B and leaves only A(it+1) in flight)
        bf16x8 ball[4][4];
#pragma unroll
        for (int s = 0; s < 4; ++s) {
            const int t = s >> 1, ks = s & 1;
            const int jb = t * 64 + it * 8 + ks * 4 + quad;
            const unsigned short* bbase = WpT + ((size_t)jb * 512 + co0 + wn + lm) * 8;
#pragma unroll
            for (int nt = 0; nt < 4; ++nt)
                ball[s][nt] = *(const bf16x8*)(bbase + (size_t)nt * 16 * 8);
        }

        if (it < 7) {
            issueA(it + 1);
            __builtin_amdgcn_s_waitcnt(0xF79);   // vmcnt(9): B(it)+A(it) done
        } else {
            __builtin_amdgcn_s_waitcnt(0xF70);   // vmcnt(0)
        }
        __asm__ volatile("" ::: "memory");

        const unsigned short* buf = (it & 1) ? slot1 : slot0;

        // A-frag read for step s (rows are wave-local: window starts at wm-8)
        auto loadA = [&](int s, bf16x8* af) {
            const int t = s >> 1, ks = s & 1;
            const int shift = t ? d : 0;
            const int rowoff = 8 - shift;                  // within 72-row window
            const int key = (8 - shift + lm) & 7;
            const int cpos = ((ks * 4 + quad) ^ key);
#pragma unroll
            for (int mt = 0; mt < 4; ++mt)
                af[mt] = *(const bf16x8*)&buf[(rowoff + mt * 16 + lm) * 64 + cpos * 8];
        };

        bf16x8 afc[4], afn[4];
        loadA(0, afc);
#pragma unroll
        for (int s = 0; s < 4; ++s) {
            if (s < 3) loadA(s + 1, afn);
#pragma unroll
            for (int mt = 0; mt < 4; ++mt)
#pragma unroll
                for (int nt = 0; nt < 4; ++nt)
                    acc[mt][nt] = __builtin_amdgcn_mfma_f32_16x16x32_bf16(
                        afc[mt], ball[s][nt], acc[mt][nt], 0, 0, 0);
            if (s < 3) {
#pragma unroll
                for (int q2 = 0; q2 < 4; ++q2) afc[q2] = afn[q2];
            }
        }
    }

    // epilogue: C/D layout col(co)=lane&15, row(n)=quad*4+reg
    float bv[4];
#pragma unroll
    for (int nt = 0; nt < 4; ++nt) bv[nt] = bias[co0 + wn + nt * 16 + lm];

#pragma unroll
    for (int mt = 0; mt < 4; ++mt) {
        int prow0 = rbase + wm + mt * 16 + quad * 4;
#pragma unroll
        for (int nt = 0; nt < 4; ++nt) {
            int co = co0 + wn + nt * 16 + lm;
#pragma unroll
            for (int r = 0; r < 4; ++r) {
                size_t off = (size_t)(prow0 + r) * CC + co;
                float v = acc[mt][nt][r] + bv[nt];
                v = fmaxf(v, 0.f);
                if (HAS_RES) {
                    v += bf2f(resB[off]);
                    v = fmaxf(v, 0.f);
                }
                OutB[off] = f2bf(v);
            }
        }
    }
}

// decode as per-wave MFMA mini-GEMM: M=16 n, N=16 o (11 real), K=512.
__global__ __launch_bounds__(256) void decode_kernel(
    const unsigned short* __restrict__ H, const unsigned short* __restrict__ dwp,
    const float* __restrict__ db, const int* __restrict__ mask,
    float* __restrict__ out)
{
    const int wave = threadIdx.x >> 6, lane = threadIdx.x & 63;
    const int lm = lane & 15, quad = lane >> 4;
    const int n0 = blockIdx.x * 64 + wave * 16;    // 64-aligned: no seq crossing
    const int prow = ((n0 + lm) >> 10) * LROWS + LPAD + ((n0 + lm) & (LL - 1));

    f32x4 acc = (f32x4){0.f, 0.f, 0.f, 0.f};
#pragma unroll
    for (int ks = 0; ks < 16; ++ks) {
        bf16x8 af = *(const bf16x8*)&H[(size_t)prow * CC + ks * 32 + quad * 8];
        bf16x8 bf = *(const bf16x8*)&dwp[((size_t)(ks * 4 + quad) * 16 + lm) * 8];
        acc = __builtin_amdgcn_mfma_f32_16x16x32_bf16(af, bf, acc, 0, 0, 0);
    }

    if (lm < OUTD) {
        float bo = db[lm];
#pragma unroll
        for (int r = 0; r < 4; ++r) {
            int n = n0 + quad * 4 + r;
            float v = (mask[n] != 0) ? (acc[r] + bo) : 0.f;
            out[(size_t)n * OUTD + lm] = v;
        }
    }
}

extern "C" void kernel_launch(void* const* d_in, const int* in_sizes, int n_in,
                              void* d_out, int out_size, void* d_ws, size_t ws_size,
                              hipStream_t stream)
{
    const int* x = (const int*)d_in[0];
    const int* mask = (const int*)d_in[1];   // jnp bool_ staged as int32
    const float* emb = (const float*)d_in[2];
    const float* w1 = (const float*)d_in[3];
    const float* b1 = (const float*)d_in[4];
    const float* w2 = (const float*)d_in[5];
    const float* b2 = (const float*)d_in[6];
    const float* dw = (const float*)d_in[7];
    const float* db = (const float*)d_in[8];
    float* out = (float*)d_out;

    char* ws = (char*)d_ws;
    const size_t HBB = (size_t)BB * LROWS * CC * 2;       // 33.8 MB (padded bf16)
    unsigned short* Hb0 = (unsigned short*)ws;
    unsigned short* Hb1 = (unsigned short*)(ws + HBB);
    unsigned short* WpT = (unsigned short*)(ws + 2 * HBB); // k-major bf16 weights, 8 MB
    unsigned short* dwp = (unsigned short*)(ws + 2 * HBB + (size_t)NLEVS * 2 * CC * 1024 * 2);

    prep_kernel<<<24736, 256, 0, stream>>>(x, emb, w1, w2, dw, Hb0, Hb1, WpT, dwp);

    const int grid = (CC / 128) * (NN / 128);   // 4 * 256 = 1024 blocks
    for (int i = 0; i < NLEVS; ++i) {
        int d = 1 << i;
        const unsigned short* W1 = WpT + (size_t)(i * 2 + 0) * CC * 1024;
        const unsigned short* W2 = WpT + (size_t)(i * 2 + 1) * CC * 1024;
        // conv1: A=Hb0 -> Hb1
        conv_gemm<false><<<grid, 256, 0, stream>>>(Hb0, W1, b1 + i * CC, nullptr, Hb1, d);
        // conv2: A=Hb1, res=Hb0 (bf16), out=Hb0 (in place, lane-owned)
        conv_gemm<true><<<grid, 256, 0, stream>>>(Hb1, W2, b2 + i * CC, Hb0, Hb0, d);
    }
    decode_kernel<<<NN / 64, 256, 0, stream>>>(Hb0, dwp, db, mask, out);
}